// Round 18
// baseline (24.127 us; speedup 1.0000x reference)
//
#include <hip/hip_runtime.h>

// B=8192, D=1024, C=90, K=16.
// R18 = R14 (best, 22.9us) with the dots-kernel prologue de-serialized:
//  (1) bin_split (R14) + tail-padding: lists[c][count..192) = -1 sentinel.
//  (2) quad_dots_static: block -> (XCD group g=b&7, class-in-group, quad
//      pair) by ARITHMETIC (no counts load, no 16-step scan, no ballot):
//      prologue = one broadcast int load (first id of the pair range;
//      <0 => whole block dead, uniform exit) + one int4 per wave-pair.
//      Sample gates come from id signs (padding is a suffix). Compute
//      core (D-half waves, 4-k-group REDUCE16, pair epilogue) verbatim.
//  (3) reduce_final: 4608 partials -> mean. No atomics anywhere.

#define B_SAMP  8192
#define K_SUB   16
#define C_CLS   90
#define LISTCAP 192             // per-class capacity (mean 91, ~10 sigma)
#define F4_ROW  256             // float4 per D=1024 row
#define NSLOT   12              // class slots per XCD group
#define QPAIR   24              // quad-pairs per class (24*8 = 192 samples)
#define NBLK    (8 * NSLOT * QPAIR)   // 2304
#define NPART   (NBLK * 2)            // 4608

// ws layout (bytes)
#define OFF_LISTS  4096         // 90*192 ints
#define OFF_PART   (1u << 20)   // NPART floats

template <int CTRL>
__device__ __forceinline__ float dpp_qperm(float v) {
    return __int_as_float(__builtin_amdgcn_update_dpp(
        0, __float_as_int(v), CTRL, 0xF, 0xF, true));
}

__device__ __forceinline__ float dot8(float4 q0, float4 q1, float4 y0, float4 y1)
{
    float t = 0.0f;
    t = fmaf(y0.x, q0.x, t); t = fmaf(y0.y, q0.y, t);
    t = fmaf(y0.z, q0.z, t); t = fmaf(y0.w, q0.w, t);
    t = fmaf(y1.x, q1.x, t); t = fmaf(y1.y, q1.y, t);
    t = fmaf(y1.z, q1.z, t); t = fmaf(y1.w, q1.w, t);
    return t;
}

// 16-lane-group epilogue (verified R6-R17).
__device__ __forceinline__ float sample_loss16(float r, int kk)
{
    const float d = 1.0f - r;
    float S = d;
    S += __shfl_xor(S, 1, 64);
    S += __shfl_xor(S, 2, 64);
    S += __shfl_xor(S, 4, 64);
    S += __shfl_xor(S, 8, 64);
    float dmin = d;
    dmin = fminf(dmin, __shfl_xor(dmin, 1, 64));
    dmin = fminf(dmin, __shfl_xor(dmin, 2, 64));
    dmin = fminf(dmin, __shfl_xor(dmin, 4, 64));
    dmin = fminf(dmin, __shfl_xor(dmin, 8, 64));
    int cand = (d == dmin) ? kk : 99;      // first-min == jnp.argmin
    cand = min(cand, __shfl_xor(cand, 1, 64));
    cand = min(cand, __shfl_xor(cand, 2, 64));
    cand = min(cand, __shfl_xor(cand, 4, 64));
    cand = min(cand, __shfl_xor(cand, 8, 64));
    const float inv = 1.0f / S;
    float t = (kk == cand) ? (d * d * inv)            // term1
                           : ((1.0f - d * inv) * d);  // term2
    t += __shfl_xor(t, 1, 64);
    t += __shfl_xor(t, 2, 64);
    t += __shfl_xor(t, 4, 64);
    t += __shfl_xor(t, 8, 64);
    return t;
}

// ------- Kernel 1: split binning (R14) + -1 tail padding -------
__global__ __launch_bounds__(256) void bin_split(
    const int* __restrict__ labels,
    int*       __restrict__ lists)
{
    const int c    = blockIdx.x >> 1;
    const int h    = blockIdx.x & 1;
    const int tid  = threadIdx.x;
    const int wave = tid >> 6;
    const int lane = tid & 63;
    __shared__ int wcnt[4];
    __shared__ int b0_sh;

    const int4* lv = reinterpret_cast<const int4*>(labels);

    if (h == 1) {
        int c0 = 0;
#pragma unroll
        for (int it = 0; it < 4; ++it) {
            const int4 l4 = lv[wave * 256 + it * 64 + lane];
            c0 += (l4.x == c) + (l4.y == c) + (l4.z == c) + (l4.w == c);
        }
#pragma unroll
        for (int off = 32; off > 0; off >>= 1) c0 += __shfl_xor(c0, off, 64);
        if (lane == 0) wcnt[wave] = c0;
        __syncthreads();
        if (tid == 0) b0_sh = wcnt[0] + wcnt[1] + wcnt[2] + wcnt[3];
        __syncthreads();
    } else {
        if (tid == 0) b0_sh = 0;
        __syncthreads();
    }
    const int hbase = b0_sh;

    const int4* hv = lv + h * 1024;

    int4 seg[4];
    int cnt = 0;
#pragma unroll
    for (int it = 0; it < 4; ++it) {
        seg[it] = hv[wave * 256 + it * 64 + lane];
        cnt += (seg[it].x == c) + (seg[it].y == c) + (seg[it].z == c) + (seg[it].w == c);
    }
#pragma unroll
    for (int off = 32; off > 0; off >>= 1) cnt += __shfl_xor(cnt, off, 64);
    if (lane == 0) wcnt[wave] = cnt;
    __syncthreads();

    int base = hbase;
    for (int w = 0; w < wave; ++w) base += wcnt[w];
    const int htotal = wcnt[0] + wcnt[1] + wcnt[2] + wcnt[3];

#pragma unroll
    for (int it = 0; it < 4; ++it) {
        const int idx0 = h * 4096 + (wave * 256 + it * 64 + lane) * 4;
        const int ls[4] = { seg[it].x, seg[it].y, seg[it].z, seg[it].w };
#pragma unroll
        for (int u = 0; u < 4; ++u) {
            const bool hit = (ls[u] == c);
            const unsigned long long m = __ballot(hit);
            if (hit) {
                const int p = base + (int)__popcll(m & ((1ull << lane) - 1ull));
                if (p < LISTCAP) lists[c * LISTCAP + p] = idx0 + u;
            }
            base += (int)__popcll(m);
        }
    }
    // h==1 knows the full count: pad the tail with -1 sentinels.
    if (h == 1) {
        int total = hbase + htotal;
        if (total > LISTCAP) total = LISTCAP;
        for (int p = total + tid; p < LISTCAP; p += 256)
            lists[c * LISTCAP + p] = -1;
    }
}

// -------- Kernel 2: static-mapped quad dots (R14 compute core) --------
__global__ __launch_bounds__(256) void quad_dots_static(
    const float* __restrict__ x,
    const float* __restrict__ centers,
    const int*   __restrict__ lists,
    float*       __restrict__ partials)
{
    const int b    = blockIdx.x;
    const int g    = b & 7;                 // XCD group: classes c == g (mod 8)
    const int slot = b >> 3;                // 0..287
    const int ci   = slot / QPAIR;          // class-in-group 0..11
    const int pr   = slot % QPAIR;          // quad-pair 0..23
    const int cls  = g + 8 * ci;
    const int tid  = threadIdx.x;
    const int wv   = tid >> 6;
    const int lane = tid & 63;
    const int pair = wv >> 1;               // 0 or 1: which quad
    const int h    = wv & 1;                // D-half

    __shared__ float sdots[4][4][16];       // [wave][sample][k]
    __shared__ float sgate[2][4];           // [pair][sample]

    // ---- arithmetic prologue: one broadcast load decides block-dead ----
    if (cls >= C_CLS || lists[cls * LISTCAP + 8 * pr] < 0) {
        if (tid < 2) partials[b * 2 + tid] = 0.0f;
        return;                             // uniform, pre-barrier
    }

    const int base = 8 * pr + 4 * pair;     // this pair's quad start
    const int4 grp = *reinterpret_cast<const int4*>(lists + cls * LISTCAP + base);
    const bool livepair = (grp.x >= 0);     // wave-uniform (suffix padding)

    if (livepair) {
        int id[4];
        id[0] = grp.x;
        id[1] = (grp.y >= 0) ? grp.y : grp.x;
        id[2] = (grp.z >= 0) ? grp.z : grp.x;
        id[3] = (grp.w >= 0) ? grp.w : grp.x;

        // x rows: this wave's D-half only -> x fetched exactly once per row.
        const float4* xv = reinterpret_cast<const float4*>(x);
        float4 xr[4][2];
#pragma unroll
        for (int s = 0; s < 4; ++s) {
            const size_t xo = (size_t)id[s] * F4_ROW + h * 128;
            xr[s][0] = xv[xo + lane];
            xr[s][1] = xv[xo + 64 + lane];
        }

        const float4* cb = reinterpret_cast<const float4*>(centers)
                         + (size_t)cls * (K_SUB * F4_ROW) + h * 128 + lane;

        const bool b0 = (lane & 1) != 0;
        const bool b1 = (lane & 2) != 0;
        const bool b2 = (lane & 4) != 0;
        const bool b3 = (lane & 8) != 0;
        const int kmap = 8 * (lane & 1) + 4 * ((lane >> 1) & 1)
                       + 2 * ((lane >> 2) & 1) + ((lane >> 3) & 1);

#define REDUCE16(A, OUT)                                                      \
    {                                                                         \
        _Pragma("unroll")                                                     \
        for (int jj = 0; jj < 8; ++jj) {                                      \
            const float send = b0 ? A[jj] : A[jj + 8];                        \
            const float recv = dpp_qperm<0xB1>(send);       /* xor 1 */       \
            A[jj] = (b0 ? A[jj + 8] : A[jj]) + recv;                          \
        }                                                                     \
        _Pragma("unroll")                                                     \
        for (int jj = 0; jj < 4; ++jj) {                                      \
            const float send = b1 ? A[jj] : A[jj + 4];                        \
            const float recv = dpp_qperm<0x4E>(send);       /* xor 2 */       \
            A[jj] = (b1 ? A[jj + 4] : A[jj]) + recv;                          \
        }                                                                     \
        _Pragma("unroll")                                                     \
        for (int jj = 0; jj < 2; ++jj) {                                      \
            const float send = b2 ? A[jj] : A[jj + 2];                        \
            const float recv = __shfl_xor(send, 4, 64);                       \
            A[jj] = (b2 ? A[jj + 2] : A[jj]) + recv;                          \
        }                                                                     \
        {                                                                     \
            const float send = b3 ? A[0] : A[1];                              \
            const float recv = __shfl_xor(send, 8, 64);                       \
            A[0] = (b3 ? A[1] : A[0]) + recv;                                 \
        }                                                                     \
        A[0] += __shfl_xor(A[0], 16, 64);                                     \
        A[0] += __shfl_xor(A[0], 32, 64);                                     \
        OUT = A[0];                                                           \
    }

        // 4 k-groups: only 16 accumulators live at a time (low VGPR).
#pragma unroll
        for (int kq = 0; kq < 4; ++kq) {
            float A[16];
#pragma unroll
            for (int kk = 0; kk < 4; ++kk) {
                const int k = kq * 4 + kk;
                const float4 q0 = cb[k * F4_ROW];
                const float4 q1 = cb[k * F4_ROW + 64];
                A[0 * 4 + kk] = dot8(q0, q1, xr[0][0], xr[0][1]);
                A[1 * 4 + kk] = dot8(q0, q1, xr[1][0], xr[1][1]);
                A[2 * 4 + kk] = dot8(q0, q1, xr[2][0], xr[2][1]);
                A[3 * 4 + kk] = dot8(q0, q1, xr[3][0], xr[3][1]);
            }
            float r;
            REDUCE16(A, r)
            if (lane < 16) sdots[wv][kmap >> 2][kq * 4 + (kmap & 3)] = r;
        }
#undef REDUCE16

        if (h == 0 && lane < 4) {
            const int raw = (lane == 0) ? grp.x : (lane == 1) ? grp.y
                          : (lane == 2) ? grp.z : grp.w;
            sgate[pair][lane] = (raw >= 0) ? 1.0f : 0.0f;
        }
    } else {
        // dead pair: zero its sdots half + gates, then join the barrier
        if (lane < 16) {
#pragma unroll
            for (int s = 0; s < 4; ++s) sdots[wv][s][lane] = 0.0f;
        }
        if (h == 0 && lane < 4) sgate[pair][lane] = 0.0f;
    }

    __syncthreads();

    // epilogue: wave 0 -> pair 0, wave 1 -> pair 1
    if (wv < 2) {
        const int s  = lane >> 4;
        const int kk = lane & 15;
        const float r = sdots[wv * 2][s][kk] + sdots[wv * 2 + 1][s][kk];
        float wl = sample_loss16(r, kk) * sgate[wv][s];
        wl += __shfl_xor(wl, 16, 64);
        wl += __shfl_xor(wl, 32, 64);
        if (lane == 0) partials[b * 2 + wv] = wl;
    }
}

// ---------------- Kernel 3: final mean, 1024 threads ----------------
__global__ __launch_bounds__(1024) void reduce_final(
    const float* __restrict__ partials,
    float*       __restrict__ out)
{
    const int tid  = threadIdx.x;
    const int wave = tid >> 6;
    const int lane = tid & 63;
    float s = 0.0f;
    for (int i = tid; i < NPART; i += 1024) s += partials[i];
#pragma unroll
    for (int off = 32; off > 0; off >>= 1) s += __shfl_xor(s, off, 64);
    __shared__ float w[16];
    if (lane == 0) w[wave] = s;
    __syncthreads();
    if (wave == 0) {
        float v = (lane < 16) ? w[lane] : 0.0f;
#pragma unroll
        for (int off = 8; off > 0; off >>= 1) v += __shfl_xor(v, off, 64);
        if (lane == 0) out[0] = v * (1.0f / (float)B_SAMP);
    }
}

extern "C" void kernel_launch(void* const* d_in, const int* in_sizes, int n_in,
                              void* d_out, int out_size, void* d_ws, size_t ws_size,
                              hipStream_t stream)
{
    const float* x       = (const float*)d_in[0];
    const int*   labels  = (const int*)  d_in[1];
    const float* centers = (const float*)d_in[2];
    float*       out     = (float*)d_out;
    char*        ws      = (char*)d_ws;

    int*   lists  = (int*)  (ws + OFF_LISTS);
    float* parts  = (float*)(ws + OFF_PART);

    bin_split       <<<C_CLS * 2, 256,  0, stream>>>(labels, lists);
    quad_dots_static<<<NBLK,      256,  0, stream>>>(x, centers, lists, parts);
    reduce_final    <<<1,         1024, 0, stream>>>(parts, out);
}

// Round 19
// 22.828 us; speedup vs baseline: 1.0569x; 1.0569x over previous
//
#include <hip/hip_runtime.h>

// B=8192, D=1024, C=90, K=16.
// R19 = R14 VERBATIM (session champion, 22.9 us) - final revert.
//  (1) bin_split: 180 blocks = (class, label-half); halved ballot chain.
//  (2) quad_dots: wave = 4 same-class samples x D-half, XCD-pinned classes
//      via b&7, 4-k-group REDUCE16 (DPP+shfl), pair epilogue. (R9 core.)
//  (3) reduce_final: 1024 threads.
// No atomics anywhere (R6/R11/R13: device-scope atomic tails are 2-4x toxic).
// Plateau note: six structural rewrites (R12/R15/R16/R17/R18) all landed
// 23.1-26.5 us; no pipe is saturated (HBM ~5us, L2 ~4us, VALU ~4us worth of
// work) - bound by dependent-chain latency of small-grid gather work.

#define B_SAMP  8192
#define K_SUB   16
#define C_CLS   90
#define LISTCAP 192             // per-class capacity (mean 91, ~10 sigma)
#define F4_ROW  256             // float4 per D=1024 row
#define TSLOT   192             // block slots per XCD group (2 quads each)
#define NBLK    (8 * TSLOT)     // 1536
#define NPART   (NBLK * 2)

// ws layout (bytes)
#define OFF_COUNTS 0            // 90 ints
#define OFF_LISTS  4096         // 90*192 ints
#define OFF_PART   (1u << 20)   // NPART floats

template <int CTRL>
__device__ __forceinline__ float dpp_qperm(float v) {
    return __int_as_float(__builtin_amdgcn_update_dpp(
        0, __float_as_int(v), CTRL, 0xF, 0xF, true));
}

__device__ __forceinline__ float dot8(float4 q0, float4 q1, float4 y0, float4 y1)
{
    float t = 0.0f;
    t = fmaf(y0.x, q0.x, t); t = fmaf(y0.y, q0.y, t);
    t = fmaf(y0.z, q0.z, t); t = fmaf(y0.w, q0.w, t);
    t = fmaf(y1.x, q1.x, t); t = fmaf(y1.y, q1.y, t);
    t = fmaf(y1.z, q1.z, t); t = fmaf(y1.w, q1.w, t);
    return t;
}

// 16-lane-group epilogue (verified R6-R18).
__device__ __forceinline__ float sample_loss16(float r, int kk)
{
    const float d = 1.0f - r;
    float S = d;
    S += __shfl_xor(S, 1, 64);
    S += __shfl_xor(S, 2, 64);
    S += __shfl_xor(S, 4, 64);
    S += __shfl_xor(S, 8, 64);
    float dmin = d;
    dmin = fminf(dmin, __shfl_xor(dmin, 1, 64));
    dmin = fminf(dmin, __shfl_xor(dmin, 2, 64));
    dmin = fminf(dmin, __shfl_xor(dmin, 4, 64));
    dmin = fminf(dmin, __shfl_xor(dmin, 8, 64));
    int cand = (d == dmin) ? kk : 99;      // first-min == jnp.argmin
    cand = min(cand, __shfl_xor(cand, 1, 64));
    cand = min(cand, __shfl_xor(cand, 2, 64));
    cand = min(cand, __shfl_xor(cand, 4, 64));
    cand = min(cand, __shfl_xor(cand, 8, 64));
    const float inv = 1.0f / S;
    float t = (kk == cand) ? (d * d * inv)            // term1
                           : ((1.0f - d * inv) * d);  // term2
    t += __shfl_xor(t, 1, 64);
    t += __shfl_xor(t, 2, 64);
    t += __shfl_xor(t, 4, 64);
    t += __shfl_xor(t, 8, 64);
    return t;
}

// ------- Kernel 1: split binning, block = (class, half of labels) -------
__global__ __launch_bounds__(256) void bin_split(
    const int* __restrict__ labels,
    int*       __restrict__ counts,
    int*       __restrict__ lists)
{
    const int c    = blockIdx.x >> 1;
    const int h    = blockIdx.x & 1;        // label half: [0,4096) or [4096,8192)
    const int tid  = threadIdx.x;
    const int wave = tid >> 6;
    const int lane = tid & 63;
    __shared__ int wcnt[4];
    __shared__ int b0_sh;

    const int4* lv = reinterpret_cast<const int4*>(labels);

    // h==1: count-only pass over half 0 (no ballots; cheap)
    if (h == 1) {
        int c0 = 0;
#pragma unroll
        for (int it = 0; it < 4; ++it) {
            const int4 l4 = lv[wave * 256 + it * 64 + lane];
            c0 += (l4.x == c) + (l4.y == c) + (l4.z == c) + (l4.w == c);
        }
#pragma unroll
        for (int off = 32; off > 0; off >>= 1) c0 += __shfl_xor(c0, off, 64);
        if (lane == 0) wcnt[wave] = c0;
        __syncthreads();
        if (tid == 0) b0_sh = wcnt[0] + wcnt[1] + wcnt[2] + wcnt[3];
        __syncthreads();
    } else {
        if (tid == 0) b0_sh = 0;
        __syncthreads();
    }
    const int hbase = b0_sh;

    // own half: standard 2-pass ballot scatter (4 int4-iters per wave)
    const int4* hv = lv + h * 1024;         // 4096 labels = 1024 int4

    int4 seg[4];
    int cnt = 0;
#pragma unroll
    for (int it = 0; it < 4; ++it) {
        seg[it] = hv[wave * 256 + it * 64 + lane];
        cnt += (seg[it].x == c) + (seg[it].y == c) + (seg[it].z == c) + (seg[it].w == c);
    }
#pragma unroll
    for (int off = 32; off > 0; off >>= 1) cnt += __shfl_xor(cnt, off, 64);
    if (lane == 0) wcnt[wave] = cnt;
    __syncthreads();

    int base = hbase;
    for (int w = 0; w < wave; ++w) base += wcnt[w];
    const int htotal = wcnt[0] + wcnt[1] + wcnt[2] + wcnt[3];

#pragma unroll
    for (int it = 0; it < 4; ++it) {
        const int idx0 = h * 4096 + (wave * 256 + it * 64 + lane) * 4;
        const int ls[4] = { seg[it].x, seg[it].y, seg[it].z, seg[it].w };
#pragma unroll
        for (int u = 0; u < 4; ++u) {
            const bool hit = (ls[u] == c);
            const unsigned long long m = __ballot(hit);
            if (hit) {
                const int p = base + (int)__popcll(m & ((1ull << lane) - 1ull));
                if (p < LISTCAP) lists[c * LISTCAP + p] = idx0 + u;
            }
            base += (int)__popcll(m);
        }
    }
    // h==1 knows the full count (hbase + its half's total)
    if (h == 1 && tid == 0) {
        const int total = hbase + htotal;
        counts[c] = (total <= LISTCAP) ? total : LISTCAP;
    }
}

// -------- Kernel 2: R9's quad_dots VERBATIM --------
__global__ __launch_bounds__(256) void quad_dots(
    const float* __restrict__ x,
    const float* __restrict__ centers,
    const int*   __restrict__ counts,
    const int*   __restrict__ lists,
    float*       __restrict__ partials)
{
    const int b    = blockIdx.x;
    const int g    = b & 7;                 // XCD group: classes c == g (mod 8)
    const int t    = b >> 3;
    const int tid  = threadIdx.x;
    const int wv   = tid >> 6;
    const int lane = tid & 63;
    const int pair = wv >> 1;               // 0 or 1: which quad
    const int h    = wv & 1;                // D-half

    __shared__ float sdots[4][4][16];       // [wave][sample][k]
    __shared__ float sgate[2][4];           // [pair][sample]

    // ---- 16-lane register scan: quad j -> (class, offset) ----
    const int cl  = g + 8 * lane;                       // lane<12 relevant
    const int n_l = (lane < 12 && cl < C_CLS) ? counts[cl] : 0;
    const int q_l = (n_l + 3) >> 2;                     // quads in this class
    int inc = q_l;
#pragma unroll
    for (int off = 1; off < 16; off <<= 1) {
        const int v = __shfl_up(inc, off, 64);
        if (lane >= off) inc += v;
    }
    const int Qg  = __shfl(inc, 15, 64);                // total quads in group
    const int exc = inc - q_l;

    const int j = 2 * t + pair;                         // this pair's quad id

    if (2 * t >= Qg) {                                  // dead block (uniform)
        if (tid < 2) partials[b * 2 + tid] = 0.0f;
        return;
    }

    const bool livepair = (j < Qg);                     // wave-uniform

    if (livepair) {
        const bool hit = (lane < 16) && (q_l > 0) && (j >= exc) && (j < inc);
        const unsigned long long m = __ballot(hit);
        const int ls   = (int)__ffsll(m) - 1;
        const int cls  = g + 8 * ls;
        const int qoff = j - __shfl(exc, ls, 64);
        const int cntc = __shfl(n_l, ls, 64);
        const int base = qoff * 4;                      // < cntc always

        const int4 grp = *reinterpret_cast<const int4*>(lists + cls * LISTCAP + base);
        int id[4];
        id[0] = grp.x;
        id[1] = (base + 1 < cntc) ? grp.y : grp.x;
        id[2] = (base + 2 < cntc) ? grp.z : grp.x;
        id[3] = (base + 3 < cntc) ? grp.w : grp.x;

        // x rows: this wave's D-half only -> x fetched exactly once per row.
        const float4* xv = reinterpret_cast<const float4*>(x);
        float4 xr[4][2];
#pragma unroll
        for (int s = 0; s < 4; ++s) {
            const size_t xo = (size_t)id[s] * F4_ROW + h * 128;
            xr[s][0] = xv[xo + lane];
            xr[s][1] = xv[xo + 64 + lane];
        }

        const float4* cb = reinterpret_cast<const float4*>(centers)
                         + (size_t)cls * (K_SUB * F4_ROW) + h * 128 + lane;

        const bool b0 = (lane & 1) != 0;
        const bool b1 = (lane & 2) != 0;
        const bool b2 = (lane & 4) != 0;
        const bool b3 = (lane & 8) != 0;
        const int kmap = 8 * (lane & 1) + 4 * ((lane >> 1) & 1)
                       + 2 * ((lane >> 2) & 1) + ((lane >> 3) & 1);

#define REDUCE16(A, OUT)                                                      \
    {                                                                         \
        _Pragma("unroll")                                                     \
        for (int jj = 0; jj < 8; ++jj) {                                      \
            const float send = b0 ? A[jj] : A[jj + 8];                        \
            const float recv = dpp_qperm<0xB1>(send);       /* xor 1 */       \
            A[jj] = (b0 ? A[jj + 8] : A[jj]) + recv;                          \
        }                                                                     \
        _Pragma("unroll")                                                     \
        for (int jj = 0; jj < 4; ++jj) {                                      \
            const float send = b1 ? A[jj] : A[jj + 4];                        \
            const float recv = dpp_qperm<0x4E>(send);       /* xor 2 */       \
            A[jj] = (b1 ? A[jj + 4] : A[jj]) + recv;                          \
        }                                                                     \
        _Pragma("unroll")                                                     \
        for (int jj = 0; jj < 2; ++jj) {                                      \
            const float send = b2 ? A[jj] : A[jj + 2];                        \
            const float recv = __shfl_xor(send, 4, 64);                       \
            A[jj] = (b2 ? A[jj + 2] : A[jj]) + recv;                          \
        }                                                                     \
        {                                                                     \
            const float send = b3 ? A[0] : A[1];                              \
            const float recv = __shfl_xor(send, 8, 64);                       \
            A[0] = (b3 ? A[1] : A[0]) + recv;                                 \
        }                                                                     \
        A[0] += __shfl_xor(A[0], 16, 64);                                     \
        A[0] += __shfl_xor(A[0], 32, 64);                                     \
        OUT = A[0];                                                           \
    }

        // 4 k-groups: only 16 accumulators live at a time (low VGPR).
#pragma unroll
        for (int kq = 0; kq < 4; ++kq) {
            float A[16];
#pragma unroll
            for (int kk = 0; kk < 4; ++kk) {
                const int k = kq * 4 + kk;
                const float4 q0 = cb[k * F4_ROW];
                const float4 q1 = cb[k * F4_ROW + 64];
                A[0 * 4 + kk] = dot8(q0, q1, xr[0][0], xr[0][1]);
                A[1 * 4 + kk] = dot8(q0, q1, xr[1][0], xr[1][1]);
                A[2 * 4 + kk] = dot8(q0, q1, xr[2][0], xr[2][1]);
                A[3 * 4 + kk] = dot8(q0, q1, xr[3][0], xr[3][1]);
            }
            float r;
            REDUCE16(A, r)
            if (lane < 16) sdots[wv][kmap >> 2][kq * 4 + (kmap & 3)] = r;
        }
#undef REDUCE16

        if (h == 0 && lane < 4)
            sgate[pair][lane] = (base + lane < cntc) ? 1.0f : 0.0f;
    } else {
        // dead pair: zero its sdots half + gates, then join the barrier
        if (lane < 16) {
#pragma unroll
            for (int s = 0; s < 4; ++s) sdots[wv][s][lane] = 0.0f;
        }
        if (h == 0 && lane < 4) sgate[pair][lane] = 0.0f;
    }

    __syncthreads();

    // epilogue: wave 0 -> pair 0, wave 1 -> pair 1
    if (wv < 2) {
        const int s  = lane >> 4;
        const int kk = lane & 15;
        const float r = sdots[wv * 2][s][kk] + sdots[wv * 2 + 1][s][kk];
        float wl = sample_loss16(r, kk) * sgate[wv][s];
        wl += __shfl_xor(wl, 16, 64);
        wl += __shfl_xor(wl, 32, 64);
        if (lane == 0) partials[b * 2 + wv] = wl;
    }
}

// ---------------- Kernel 3: final mean, 1024 threads ----------------
__global__ __launch_bounds__(1024) void reduce_final(
    const float* __restrict__ partials,
    float*       __restrict__ out)
{
    const int tid  = threadIdx.x;
    const int wave = tid >> 6;
    const int lane = tid & 63;
    float s = 0.0f;
#pragma unroll
    for (int r = 0; r < NPART / 1024; ++r) s += partials[r * 1024 + tid];
#pragma unroll
    for (int off = 32; off > 0; off >>= 1) s += __shfl_xor(s, off, 64);
    __shared__ float w[16];
    if (lane == 0) w[wave] = s;
    __syncthreads();
    if (wave == 0) {
        float v = (lane < 16) ? w[lane] : 0.0f;
#pragma unroll
        for (int off = 8; off > 0; off >>= 1) v += __shfl_xor(v, off, 64);
        if (lane == 0) out[0] = v * (1.0f / (float)B_SAMP);
    }
}

extern "C" void kernel_launch(void* const* d_in, const int* in_sizes, int n_in,
                              void* d_out, int out_size, void* d_ws, size_t ws_size,
                              hipStream_t stream)
{
    const float* x       = (const float*)d_in[0];
    const int*   labels  = (const int*)  d_in[1];
    const float* centers = (const float*)d_in[2];
    float*       out     = (float*)d_out;
    char*        ws      = (char*)d_ws;

    int*   counts = (int*)  (ws + OFF_COUNTS);
    int*   lists  = (int*)  (ws + OFF_LISTS);
    float* parts  = (float*)(ws + OFF_PART);

    bin_split   <<<C_CLS * 2, 256,  0, stream>>>(labels, counts, lists);
    quad_dots   <<<NBLK,      256,  0, stream>>>(x, centers, counts, lists, parts);
    reduce_final<<<1,         1024, 0, stream>>>(parts, out);
}